// Round 1
// baseline (196.718 us; speedup 1.0000x reference)
//
#include <hip/hip_runtime.h>

#define BB 8
#define TT 512
#define DD 512
#define LL 24

__global__ void hs_zero_out(float* out) { out[0] = 0.0f; }

__global__ __launch_bounds__(256) void hs_kernel(
    const float* __restrict__ x,
    const float* __restrict__ node_vecs,
    const int* __restrict__ paths,
    const int* __restrict__ codes,
    const int* __restrict__ mask,
    float* __restrict__ out)
{
    const int bt   = blockIdx.x;     // 0 .. B*T-1
    const int tid  = threadIdx.x;    // 0 .. 255
    const int lane = tid & 63;
    const int wave = tid >> 6;       // 0 .. 3

    __shared__ float xs[DD];
    __shared__ float wsum[4];

    // stage x[b,t,:] into LDS (512 floats = 128 float4)
    const float4* xg  = (const float4*)(x + (size_t)bt * DD);
    float4*       xs4 = (float4*)xs;
    if (tid < DD / 4) xs4[tid] = xg[tid];
    __syncthreads();

    const int base = bt * LL;
    float local = 0.0f;

    for (int l = wave; l < LL; l += 4) {
        const int m = mask[base + l];          // wave-uniform
        if (m == 0) continue;                  // skip masked level: saves the gather
        const int idx = paths[base + l];
        const int c   = codes[base + l];

        const float4* nv = (const float4*)(node_vecs + (size_t)idx * DD);
        // coalesced: lanes 0..63 read consecutive float4s, twice
        float4 a0 = nv[lane];
        float4 a1 = nv[lane + 64];
        float4 b0 = xs4[lane];
        float4 b1 = xs4[lane + 64];

        float dot = a0.x * b0.x + a0.y * b0.y + a0.z * b0.z + a0.w * b0.w
                  + a1.x * b1.x + a1.y * b1.y + a1.z * b1.z + a1.w * b1.w;

        // 64-lane butterfly reduce (all lanes end with full dot)
        #pragma unroll
        for (int off = 32; off >= 1; off >>= 1)
            dot += __shfl_xor(dot, off, 64);

        const float sign = 1.0f - 2.0f * (float)c;
        const float z    = -sign * dot;
        // -log_sigmoid(s*dot) = softplus(-s*dot), numerically stable form
        const float nll  = fmaxf(z, 0.0f) + log1pf(expf(-fabsf(z)));
        local += nll;
    }

    if (lane == 0) wsum[wave] = local;
    __syncthreads();
    if (tid == 0) {
        const float s = wsum[0] + wsum[1] + wsum[2] + wsum[3];
        atomicAdd(out, s * (1.0f / (float)BB));
    }
}

extern "C" void kernel_launch(void* const* d_in, const int* in_sizes, int n_in,
                              void* d_out, int out_size, void* d_ws, size_t ws_size,
                              hipStream_t stream) {
    const float* x         = (const float*)d_in[0];
    const float* node_vecs = (const float*)d_in[1];
    const int*   paths     = (const int*)d_in[2];
    const int*   codes     = (const int*)d_in[3];
    const int*   mask      = (const int*)d_in[4];
    float*       out       = (float*)d_out;

    hs_zero_out<<<1, 1, 0, stream>>>(out);
    hs_kernel<<<BB * TT, 256, 0, stream>>>(x, node_vecs, paths, codes, mask, out);
}

// Round 2
// 194.287 us; speedup vs baseline: 1.0125x; 1.0125x over previous
//
#include <hip/hip_runtime.h>

#define BB 8
#define TT 512
#define DD 512
#define LL 24
#define LPW 6   // levels per wave (24 / 4 waves)

__global__ void hs_zero_out(float* out) { out[0] = 0.0f; }

__global__ __launch_bounds__(256) void hs_kernel(
    const float* __restrict__ x,
    const float* __restrict__ node_vecs,
    const int* __restrict__ paths,
    const int* __restrict__ codes,
    const int* __restrict__ mask,
    float* __restrict__ out)
{
    const int bt   = blockIdx.x;     // 0 .. B*T-1
    const int tid  = threadIdx.x;
    const int lane = tid & 63;
    const int wave = tid >> 6;       // 0 .. 3

    __shared__ float xs[DD];
    __shared__ int   mpaths[LL];
    __shared__ int   mcodes[LL];
    __shared__ int   mmask[LL];
    __shared__ float wsum[4];

    // stage x[b,t,:] into LDS (128 float4s, threads 0..127) and the 3×24-int
    // metadata (threads 128..215) — one global round-trip per block
    const float4* xg  = (const float4*)(x + (size_t)bt * DD);
    float4*       xs4 = (float4*)xs;
    const int base = bt * LL;
    if (tid < DD / 4)                      xs4[tid]          = xg[tid];
    else if (tid >= 128 && tid < 128 + LL) mpaths[tid - 128] = paths[base + tid - 128];
    else if (tid >= 160 && tid < 160 + LL) mcodes[tid - 160] = codes[base + tid - 160];
    else if (tid >= 192 && tid < 192 + LL) mmask[tid - 192]  = mask[base + tid - 192];
    __syncthreads();

    const int l0 = wave * LPW;

    const float4 b0 = xs4[lane];
    const float4 b1 = xs4[lane + 64];

    int    msk[LPW], cod[LPW];
    float4 a0[LPW], a1[LPW];

    // issue ALL 12 gather loads up front — independent, pipelined
    #pragma unroll
    for (int j = 0; j < LPW; ++j) {
        const int l = l0 + j;
        msk[j] = mmask[l];
        cod[j] = mcodes[l];
        const int idx = msk[j] ? mpaths[l] : 0;   // masked -> row 0 (cache-hot, no HBM)
        const float4* nv = (const float4*)(node_vecs + (size_t)idx * DD);
        a0[j] = nv[lane];
        a1[j] = nv[lane + 64];
    }

    float dot[LPW];
    #pragma unroll
    for (int j = 0; j < LPW; ++j) {
        dot[j] = a0[j].x * b0.x + a0[j].y * b0.y + a0[j].z * b0.z + a0[j].w * b0.w
               + a1[j].x * b1.x + a1[j].y * b1.y + a1[j].z * b1.z + a1[j].w * b1.w;
    }

    // 6 independent butterfly chains, interleaved (6 steps total depth)
    #pragma unroll
    for (int off = 32; off >= 1; off >>= 1) {
        #pragma unroll
        for (int j = 0; j < LPW; ++j)
            dot[j] += __shfl_xor(dot[j], off, 64);
    }

    float local = 0.0f;
    #pragma unroll
    for (int j = 0; j < LPW; ++j) {
        const float sign = 1.0f - 2.0f * (float)cod[j];
        const float z    = -sign * dot[j];
        const float nll  = fmaxf(z, 0.0f) + log1pf(expf(-fabsf(z)));
        local += msk[j] ? nll : 0.0f;
    }

    if (lane == 0) wsum[wave] = local;
    __syncthreads();
    if (tid == 0)
        atomicAdd(out, (wsum[0] + wsum[1] + wsum[2] + wsum[3]) * (1.0f / (float)BB));
}

extern "C" void kernel_launch(void* const* d_in, const int* in_sizes, int n_in,
                              void* d_out, int out_size, void* d_ws, size_t ws_size,
                              hipStream_t stream) {
    const float* x         = (const float*)d_in[0];
    const float* node_vecs = (const float*)d_in[1];
    const int*   paths     = (const int*)d_in[2];
    const int*   codes     = (const int*)d_in[3];
    const int*   mask      = (const int*)d_in[4];
    float*       out       = (float*)d_out;

    hs_zero_out<<<1, 1, 0, stream>>>(out);
    hs_kernel<<<BB * TT, 256, 0, stream>>>(x, node_vecs, paths, codes, mask, out);
}

// Round 3
// 166.782 us; speedup vs baseline: 1.1795x; 1.1649x over previous
//
#include <hip/hip_runtime.h>

#define BB 8
#define TT 512
#define DD 512
#define LL 24
#define LPW 6            // levels per wave (24 / 4 waves)
#define NBLK (BB * TT)   // 4096

__global__ __launch_bounds__(256) void hs_kernel(
    const float* __restrict__ x,
    const float* __restrict__ node_vecs,
    const int* __restrict__ paths,
    const int* __restrict__ codes,
    const int* __restrict__ mask,
    float* __restrict__ partials)
{
    const int bt   = blockIdx.x;     // 0 .. B*T-1
    const int tid  = threadIdx.x;
    const int lane = tid & 63;
    const int wave = tid >> 6;       // 0 .. 3

    __shared__ float xs[DD];
    __shared__ int   mpaths[LL];
    __shared__ int   mcodes[LL];
    __shared__ int   mmask[LL];
    __shared__ float wsum[4];

    // stage x[b,t,:] into LDS (128 float4s, threads 0..127) and the 3×24-int
    // metadata (threads 128..215) — one global round-trip per block
    const float4* xg  = (const float4*)(x + (size_t)bt * DD);
    float4*       xs4 = (float4*)xs;
    const int base = bt * LL;
    if (tid < DD / 4)                      xs4[tid]          = xg[tid];
    else if (tid >= 128 && tid < 128 + LL) mpaths[tid - 128] = paths[base + tid - 128];
    else if (tid >= 160 && tid < 160 + LL) mcodes[tid - 160] = codes[base + tid - 160];
    else if (tid >= 192 && tid < 192 + LL) mmask[tid - 192]  = mask[base + tid - 192];
    __syncthreads();

    const int l0 = wave * LPW;

    const float4 b0 = xs4[lane];
    const float4 b1 = xs4[lane + 64];

    int    msk[LPW], cod[LPW];
    float4 a0[LPW], a1[LPW];

    // issue ALL 12 gather loads up front — independent, pipelined
    #pragma unroll
    for (int j = 0; j < LPW; ++j) {
        const int l = l0 + j;
        msk[j] = mmask[l];
        cod[j] = mcodes[l];
        const int idx = msk[j] ? mpaths[l] : 0;   // masked -> row 0 (cache-hot)
        const float4* nv = (const float4*)(node_vecs + (size_t)idx * DD);
        a0[j] = nv[lane];
        a1[j] = nv[lane + 64];
    }

    float dot[LPW];
    #pragma unroll
    for (int j = 0; j < LPW; ++j) {
        dot[j] = a0[j].x * b0.x + a0[j].y * b0.y + a0[j].z * b0.z + a0[j].w * b0.w
               + a1[j].x * b1.x + a1[j].y * b1.y + a1[j].z * b1.z + a1[j].w * b1.w;
    }

    // 6 independent butterfly chains, interleaved (6 steps total depth)
    #pragma unroll
    for (int off = 32; off >= 1; off >>= 1) {
        #pragma unroll
        for (int j = 0; j < LPW; ++j)
            dot[j] += __shfl_xor(dot[j], off, 64);
    }

    float local = 0.0f;
    #pragma unroll
    for (int j = 0; j < LPW; ++j) {
        const float sign = 1.0f - 2.0f * (float)cod[j];
        const float z    = -sign * dot[j];
        const float nll  = fmaxf(z, 0.0f) + log1pf(expf(-fabsf(z)));
        local += msk[j] ? nll : 0.0f;
    }

    if (lane == 0) wsum[wave] = local;
    __syncthreads();
    // one plain store per block — no same-address atomic contention
    if (tid == 0)
        partials[bt] = wsum[0] + wsum[1] + wsum[2] + wsum[3];
}

__global__ __launch_bounds__(256) void hs_reduce(
    const float* __restrict__ partials, float* __restrict__ out)
{
    const int tid  = threadIdx.x;
    const int lane = tid & 63;
    const int wave = tid >> 6;
    __shared__ float wsum[4];

    float s = 0.0f;
    for (int i = tid; i < NBLK; i += 256) s += partials[i];

    #pragma unroll
    for (int off = 32; off >= 1; off >>= 1)
        s += __shfl_xor(s, off, 64);

    if (lane == 0) wsum[wave] = s;
    __syncthreads();
    if (tid == 0)
        out[0] = (wsum[0] + wsum[1] + wsum[2] + wsum[3]) * (1.0f / (float)BB);
}

extern "C" void kernel_launch(void* const* d_in, const int* in_sizes, int n_in,
                              void* d_out, int out_size, void* d_ws, size_t ws_size,
                              hipStream_t stream) {
    const float* x         = (const float*)d_in[0];
    const float* node_vecs = (const float*)d_in[1];
    const int*   paths     = (const int*)d_in[2];
    const int*   codes     = (const int*)d_in[3];
    const int*   mask      = (const int*)d_in[4];
    float*       out       = (float*)d_out;
    float*       partials  = (float*)d_ws;   // 4096 floats = 16 KB, all written each launch

    hs_kernel<<<NBLK, 256, 0, stream>>>(x, node_vecs, paths, codes, mask, partials);
    hs_reduce<<<1, 256, 0, stream>>>(partials, out);
}

// Round 4
// 161.450 us; speedup vs baseline: 1.2184x; 1.0330x over previous
//
#include <hip/hip_runtime.h>

#define BB 8
#define TT 512
#define DD 512
#define LL 24
#define LPW 6            // levels per wave (24 / 4 waves)
#define NBLK (BB * TT)   // 4096

__global__ __launch_bounds__(256) void hs_kernel(
    const float* __restrict__ x,
    const float* __restrict__ node_vecs,
    const int* __restrict__ paths,
    const int* __restrict__ codes,
    const int* __restrict__ mask,
    float* __restrict__ partials)
{
    const int bt   = blockIdx.x;     // 0 .. B*T-1
    const int tid  = threadIdx.x;
    const int lane = tid & 63;
    const int wave = tid >> 6;       // 0 .. 3

    __shared__ int   meta[3 * LL];   // paths | codes | mask
    __shared__ float wsum[4];

    const int base = bt * LL;
    // stage the 3x24-int metadata once per block (threads 0..71)
    if (tid < LL)                     meta[tid]           = paths[base + tid];
    else if (tid >= 32 && tid < 32 + LL) meta[LL + tid - 32]  = codes[base + tid - 32];
    else if (tid >= 64 && tid < 64 + LL) meta[2*LL + tid - 64] = mask[base + tid - 64];
    __syncthreads();

    // x row direct from global: L1-resident, shared by the block's 4 waves
    const float4* xg = (const float4*)(x + (size_t)bt * DD);
    const float4 b0 = xg[lane];
    const float4 b1 = xg[lane + 64];

    const int l0 = wave * LPW;

    int    msk[LPW], cod[LPW];
    float4 a0[LPW], a1[LPW];

    // issue ALL 12 gather loads up front — independent, pipelined
    #pragma unroll
    for (int j = 0; j < LPW; ++j) {
        const int l = l0 + j;
        msk[j] = meta[2*LL + l];
        cod[j] = meta[LL + l];
        const int idx = msk[j] ? meta[l] : 0;   // masked -> row 0 (cache-hot)
        const float4* nv = (const float4*)(node_vecs + (size_t)idx * DD);
        a0[j] = nv[lane];
        a1[j] = nv[lane + 64];
    }

    float dot[LPW];
    #pragma unroll
    for (int j = 0; j < LPW; ++j) {
        dot[j] = a0[j].x * b0.x + a0[j].y * b0.y + a0[j].z * b0.z + a0[j].w * b0.w
               + a1[j].x * b1.x + a1[j].y * b1.y + a1[j].z * b1.z + a1[j].w * b1.w;
    }

    // 6 independent butterfly chains, interleaved (6 steps total depth)
    #pragma unroll
    for (int off = 32; off >= 1; off >>= 1) {
        #pragma unroll
        for (int j = 0; j < LPW; ++j)
            dot[j] += __shfl_xor(dot[j], off, 64);
    }

    float local = 0.0f;
    #pragma unroll
    for (int j = 0; j < LPW; ++j) {
        // z = -sign*dot = (2c-1)*dot ; nll = softplus(z), HW-transcendental form
        const float z   = (2.0f * (float)cod[j] - 1.0f) * dot[j];
        const float e   = __expf(-fabsf(z));           // v_exp_f32
        const float nll = fmaxf(z, 0.0f) + __logf(1.0f + e);  // v_log_f32
        local += msk[j] ? nll : 0.0f;
    }

    if (lane == 0) wsum[wave] = local;
    __syncthreads();
    if (tid == 0)
        partials[bt] = wsum[0] + wsum[1] + wsum[2] + wsum[3];
}

__global__ __launch_bounds__(256) void hs_reduce(
    const float* __restrict__ partials, float* __restrict__ out)
{
    const int tid  = threadIdx.x;
    const int lane = tid & 63;
    const int wave = tid >> 6;
    __shared__ float wsum[4];

    float s = 0.0f;
    for (int i = tid; i < NBLK; i += 256) s += partials[i];

    #pragma unroll
    for (int off = 32; off >= 1; off >>= 1)
        s += __shfl_xor(s, off, 64);

    if (lane == 0) wsum[wave] = s;
    __syncthreads();
    if (tid == 0)
        out[0] = (wsum[0] + wsum[1] + wsum[2] + wsum[3]) * (1.0f / (float)BB);
}

extern "C" void kernel_launch(void* const* d_in, const int* in_sizes, int n_in,
                              void* d_out, int out_size, void* d_ws, size_t ws_size,
                              hipStream_t stream) {
    const float* x         = (const float*)d_in[0];
    const float* node_vecs = (const float*)d_in[1];
    const int*   paths     = (const int*)d_in[2];
    const int*   codes     = (const int*)d_in[3];
    const int*   mask      = (const int*)d_in[4];
    float*       out       = (float*)d_out;
    float*       partials  = (float*)d_ws;   // 4096 floats = 16 KB, all written each launch

    hs_kernel<<<NBLK, 256, 0, stream>>>(x, node_vecs, paths, codes, mask, partials);
    hs_reduce<<<1, 256, 0, stream>>>(partials, out);
}

// Round 5
// 159.093 us; speedup vs baseline: 1.2365x; 1.0148x over previous
//
#include <hip/hip_runtime.h>

#define BB 8
#define TT 512
#define DD 512
#define LL 24
#define LPW 6            // levels per wave (24 / 4 waves)
#define NBLK (BB * TT)   // 4096
#define NPART (NBLK * 4) // 16384 per-wave partials

__global__ __launch_bounds__(256) void hs_kernel(
    const float* __restrict__ x,
    const float* __restrict__ node_vecs,
    const int* __restrict__ paths,
    const int* __restrict__ codes,
    const int* __restrict__ mask,
    float* __restrict__ partials)
{
    const int bt   = blockIdx.x;     // 0 .. B*T-1
    const int tid  = threadIdx.x;
    const int lane = tid & 63;
    const int wave = tid >> 6;       // 0 .. 3

    const int base = bt * LL + wave * LPW;

    // per-wave meta loads: same address across lanes -> 1 line each, L1-hot
    // issued straight-line, no LDS, no barrier
    int msk[LPW], cod[LPW], pth[LPW];
    #pragma unroll
    for (int j = 0; j < LPW; ++j) {
        msk[j] = mask[base + j];
        cod[j] = codes[base + j];
        pth[j] = paths[base + j];
    }

    // x row direct from global: L1-resident, shared by the block's 4 waves
    const float4* xg = (const float4*)(x + (size_t)bt * DD);
    const float4 b0 = xg[lane];
    const float4 b1 = xg[lane + 64];

    // issue ALL 12 gather loads up front — independent, pipelined
    float4 a0[LPW], a1[LPW];
    #pragma unroll
    for (int j = 0; j < LPW; ++j) {
        const int idx = msk[j] ? pth[j] : 0;   // masked -> row 0 (cache-hot)
        const float4* nv = (const float4*)(node_vecs + (size_t)idx * DD);
        a0[j] = nv[lane];
        a1[j] = nv[lane + 64];
    }

    float dot[LPW];
    #pragma unroll
    for (int j = 0; j < LPW; ++j) {
        dot[j] = a0[j].x * b0.x + a0[j].y * b0.y + a0[j].z * b0.z + a0[j].w * b0.w
               + a1[j].x * b1.x + a1[j].y * b1.y + a1[j].z * b1.z + a1[j].w * b1.w;
    }

    // 6 independent butterfly chains, interleaved (6 steps total depth)
    #pragma unroll
    for (int off = 32; off >= 1; off >>= 1) {
        #pragma unroll
        for (int j = 0; j < LPW; ++j)
            dot[j] += __shfl_xor(dot[j], off, 64);
    }

    float local = 0.0f;
    #pragma unroll
    for (int j = 0; j < LPW; ++j) {
        // z = -sign*dot = (2c-1)*dot ; nll = softplus(z), HW-transcendental form
        const float z   = (2.0f * (float)cod[j] - 1.0f) * dot[j];
        const float e   = __expf(-fabsf(z));                  // v_exp_f32
        const float nll = fmaxf(z, 0.0f) + __logf(1.0f + e);  // v_log_f32
        local += msk[j] ? nll : 0.0f;
    }

    // per-wave store — no cross-wave combine, no barrier, no atomics
    if (lane == 0) partials[bt * 4 + wave] = local;
}

__global__ __launch_bounds__(1024) void hs_reduce(
    const float* __restrict__ partials, float* __restrict__ out)
{
    const int tid  = threadIdx.x;
    const int lane = tid & 63;
    const int wave = tid >> 6;          // 0..15
    __shared__ float wsum[16];

    const float4* p4 = (const float4*)partials;   // 4096 float4s
    float s = 0.0f;
    #pragma unroll
    for (int r = 0; r < 4; ++r) {       // 4 independent vector loads, one latency round
        const float4 v = p4[tid + r * 1024];
        s += (v.x + v.y) + (v.z + v.w);
    }

    #pragma unroll
    for (int off = 32; off >= 1; off >>= 1)
        s += __shfl_xor(s, off, 64);

    if (lane == 0) wsum[wave] = s;
    __syncthreads();
    if (tid == 0) {
        float t = 0.0f;
        #pragma unroll
        for (int i = 0; i < 16; ++i) t += wsum[i];
        out[0] = t * (1.0f / (float)BB);
    }
}

extern "C" void kernel_launch(void* const* d_in, const int* in_sizes, int n_in,
                              void* d_out, int out_size, void* d_ws, size_t ws_size,
                              hipStream_t stream) {
    const float* x         = (const float*)d_in[0];
    const float* node_vecs = (const float*)d_in[1];
    const int*   paths     = (const int*)d_in[2];
    const int*   codes     = (const int*)d_in[3];
    const int*   mask      = (const int*)d_in[4];
    float*       out       = (float*)d_out;
    float*       partials  = (float*)d_ws;   // 16384 floats = 64 KB, all written each launch

    hs_kernel<<<NBLK, 256, 0, stream>>>(x, node_vecs, paths, codes, mask, partials);
    hs_reduce<<<1, 1024, 0, stream>>>(partials, out);
}

// Round 6
// 158.199 us; speedup vs baseline: 1.2435x; 1.0057x over previous
//
#include <hip/hip_runtime.h>

#define BB 8
#define TT 512
#define DD 512
#define LL 24
#define WPB 8              // waves per block
#define LPW 3              // levels per wave (24 / 8)
#define NBLK (BB * TT)     // 4096
#define NPART (NBLK * WPB) // 32768 per-wave partials

__global__ __launch_bounds__(512, 8) void hs_kernel(
    const float* __restrict__ x,
    const float* __restrict__ node_vecs,
    const int* __restrict__ paths,
    const int* __restrict__ codes,
    const int* __restrict__ mask,
    float* __restrict__ partials)
{
    const int bt   = blockIdx.x;     // 0 .. B*T-1
    const int tid  = threadIdx.x;
    const int lane = tid & 63;
    // scalarized wave index -> meta addresses provably wave-uniform -> s_load
    const int wave = __builtin_amdgcn_readfirstlane(tid >> 6);   // 0..7

    const int base = bt * LL + wave * LPW;

    // meta through the SCALAR cache (s_load): zero vector-miss-queue traffic
    int msk[LPW], cod[LPW], pth[LPW];
    #pragma unroll
    for (int j = 0; j < LPW; ++j) {
        msk[j] = mask[base + j];
        cod[j] = codes[base + j];
        pth[j] = paths[base + j];
    }

    // x row direct from global: L1-resident, shared by the block's 8 waves
    const float4* xg = (const float4*)(x + (size_t)bt * DD);
    const float4 b0 = xg[lane];
    const float4 b1 = xg[lane + 64];

    // gathers: wave-uniform branch (s_cbranch) skips masked rows entirely —
    // no dummy row-0 loads occupying the TA pipe / miss queue
    float4 a0[LPW], a1[LPW];
    #pragma unroll
    for (int j = 0; j < LPW; ++j) {
        if (msk[j]) {
            const float4* nv = (const float4*)(node_vecs + (size_t)pth[j] * DD);
            a0[j] = nv[lane];
            a1[j] = nv[lane + 64];
        } else {
            a0[j] = make_float4(0.f, 0.f, 0.f, 0.f);
            a1[j] = make_float4(0.f, 0.f, 0.f, 0.f);
        }
    }

    float dot[LPW];
    #pragma unroll
    for (int j = 0; j < LPW; ++j) {
        dot[j] = a0[j].x * b0.x + a0[j].y * b0.y + a0[j].z * b0.z + a0[j].w * b0.w
               + a1[j].x * b1.x + a1[j].y * b1.y + a1[j].z * b1.z + a1[j].w * b1.w;
    }

    // 3 independent butterfly chains, interleaved (6 steps total depth)
    #pragma unroll
    for (int off = 32; off >= 1; off >>= 1) {
        #pragma unroll
        for (int j = 0; j < LPW; ++j)
            dot[j] += __shfl_xor(dot[j], off, 64);
    }

    float local = 0.0f;
    #pragma unroll
    for (int j = 0; j < LPW; ++j) {
        // z = -sign*dot = (2c-1)*dot ; nll = softplus(z), HW transcendentals
        const float z   = (2.0f * (float)cod[j] - 1.0f) * dot[j];
        const float e   = __expf(-fabsf(z));                  // v_exp_f32
        const float nll = fmaxf(z, 0.0f) + __logf(1.0f + e);  // v_log_f32
        local += msk[j] ? nll : 0.0f;
    }

    // per-wave store — no cross-wave combine, no barrier, no atomics
    if (lane == 0) partials[bt * WPB + wave] = local;
}

__global__ __launch_bounds__(1024) void hs_reduce(
    const float* __restrict__ partials, float* __restrict__ out)
{
    const int tid  = threadIdx.x;
    const int lane = tid & 63;
    const int wave = tid >> 6;          // 0..15
    __shared__ float wsum[16];

    const float4* p4 = (const float4*)partials;   // 8192 float4s
    float s = 0.0f;
    #pragma unroll
    for (int r = 0; r < 8; ++r) {       // 8 independent vector loads, one latency round
        const float4 v = p4[tid + r * 1024];
        s += (v.x + v.y) + (v.z + v.w);
    }

    #pragma unroll
    for (int off = 32; off >= 1; off >>= 1)
        s += __shfl_xor(s, off, 64);

    if (lane == 0) wsum[wave] = s;
    __syncthreads();
    if (tid == 0) {
        float t = 0.0f;
        #pragma unroll
        for (int i = 0; i < 16; ++i) t += wsum[i];
        out[0] = t * (1.0f / (float)BB);
    }
}

extern "C" void kernel_launch(void* const* d_in, const int* in_sizes, int n_in,
                              void* d_out, int out_size, void* d_ws, size_t ws_size,
                              hipStream_t stream) {
    const float* x         = (const float*)d_in[0];
    const float* node_vecs = (const float*)d_in[1];
    const int*   paths     = (const int*)d_in[2];
    const int*   codes     = (const int*)d_in[3];
    const int*   mask      = (const int*)d_in[4];
    float*       out       = (float*)d_out;
    float*       partials  = (float*)d_ws;   // 32768 floats = 128 KB, all written each launch

    hs_kernel<<<NBLK, 512, 0, stream>>>(x, node_vecs, paths, codes, mask, partials);
    hs_reduce<<<1, 1024, 0, stream>>>(partials, out);
}